// Round 11
// baseline (880.307 us; speedup 1.0000x reference)
//
#include <hip/hip_runtime.h>
#include <hip/hip_bf16.h>

#define TT 2048
#define BB 16
#define DD 1024
#define BD (BB*DD)          // 16384 cols per time row
#define MR (TT*BB)          // 32768 GEMM rows
#define EPSV 1e-6f
#define INVD (1.0f/1024.0f)
#define CH 256              // phase-B chunk length
#define NCH (TT/CH)         // 8
#define RING 8              // scan register ring depth (rows)

// megakernel role layout: scan [0,16) | gemm [16,2064) | phaseB [2064,2576)
#define ID_GEMM   16
#define ID_PB     2064
#define ID_END    2576

typedef __bf16 bf16x8_t __attribute__((ext_vector_type(8)));
typedef float  f32x4_t  __attribute__((ext_vector_type(4)));
typedef __attribute__((address_space(1))) void gvoid_t;
typedef __attribute__((address_space(3))) void lvoid_t;

// wave64 DPP sum -> total in lane 63 -> broadcast via readlane (HW-verified v2-v10)
static __device__ __forceinline__ float wave_red_sum(float ss) {
    asm volatile(
        "s_nop 1\n\t"
        "v_add_f32 %0, %0, %0 row_shr:1 bound_ctrl:0\n\t"
        "s_nop 1\n\t"
        "v_add_f32 %0, %0, %0 row_shr:2 bound_ctrl:0\n\t"
        "s_nop 1\n\t"
        "v_add_f32 %0, %0, %0 row_shr:4 bank_mask:0xe\n\t"
        "s_nop 1\n\t"
        "v_add_f32 %0, %0, %0 row_shr:8 bank_mask:0xc\n\t"
        "s_nop 1\n\t"
        "v_add_f32 %0, %0, %0 row_bcast:15 row_mask:0xa\n\t"
        "s_nop 1\n\t"
        "v_add_f32 %0, %0, %0 row_bcast:31 row_mask:0xc\n\t"
        "s_nop 1"
        : "+v"(ss));
    return __builtin_bit_cast(float, __builtin_amdgcn_readlane(__builtin_bit_cast(int, ss), 63));
}

static __device__ __forceinline__ unsigned short f2bf(float f) {
    __hip_bfloat16 h = __float2bfloat16(f);
    return __builtin_bit_cast(unsigned short, h);
}

// ---------------------------------------------------------------------------
// K0: convert x and W to bf16 (proven body; new xb/wb placement)
// ---------------------------------------------------------------------------
__global__ void k_convert(const float* __restrict__ x, const float* __restrict__ W,
                          unsigned short* __restrict__ xb, unsigned short* __restrict__ wb) {
    const long NX4 = (long)MR * DD / 4;
    const long NW4 = (long)DD * DD / 4;
    const long stride = (long)gridDim.x * blockDim.x;
    for (long j = (long)blockIdx.x * blockDim.x + threadIdx.x; j < NX4 + NW4; j += stride) {
        const float4* src; unsigned short* dst; long o;
        if (j < NX4) { src = (const float4*)x; dst = xb; o = j; }
        else         { src = (const float4*)W; dst = wb; o = j - NX4; }
        float4 v = src[o];
        ushort4 u;
        u.x = f2bf(v.x); u.y = f2bf(v.y); u.z = f2bf(v.z); u.w = f2bf(v.w);
        *(ushort4*)(dst + o * 4) = u;
    }
}

// ---------------------------------------------------------------------------
// K_MEGA: three roles in one kernel, pipelined via device-scope flags.
//  scan  (ids 0..15):    v10's phase-A scan, + cnt[] acquire-poll per 8-row
//                        window, + prog[] release-publish per 256-step chunk.
//  gemm  (ids 16..2063): v10's bf16 MFMA gemm block (gy=(id-16)>>3), +
//                        release atomicAdd cnt[gy] on completion.
//  phaseB(ids 2064..):   v10's replay chunk, gated on prog[b] >= c+1.
// gated==0 reproduces the r10 serial pipeline exactly (fallback).
// Dead-space safety (xb at h-rows 993..2016, wb 2017..2048):
//  phaseB chunk c clobbers xb rows <= 256c+256 -> gemm y <= 64c-184, while
//  prog>=c+1 guarantees y <= 32c+33 done (holds for c<=6; c=7 needs prog=8 =
//  gemm fully done). wb clobbered only by chunk 7 (prog=8). Scan snapshots
//  at rows 256c clobber xb y <= 64c-248 <= scan-verified 32c+1. All safe.
// ---------------------------------------------------------------------------
__global__ __launch_bounds__(256, 2)
void k_mega(const unsigned short* __restrict__ A, const unsigned short* __restrict__ Bw,
            const float* __restrict__ bias, float* __restrict__ outr,
            const float* __restrict__ h0, const float* __restrict__ la,
            float* __restrict__ hreg, float* __restrict__ rtab,
            int* cnt, int* prog, int role_base, int gated) {
    __shared__ char lds[16384];
    const int id = blockIdx.x + role_base;
    const int tid = threadIdx.x;

    if (id >= ID_GEMM && id < ID_PB) {
        // ===================== GEMM role =====================
        const int gid = id - ID_GEMM;
        const int gx = gid & 7, gy = gid >> 3;
        if (gated && gy < 64) __builtin_amdgcn_s_setprio(1);   // early rows first
        char* ldsA = lds;
        char* ldsB = lds + 8192;
        const int lane = tid & 63;
        const int wid  = tid >> 6;
        const int wm = wid >> 1, wn = wid & 1;
        const size_t arow0 = (size_t)gy * 128;
        const int    brow0 = gx * 128;

        f32x4_t acc[4][4] = {};
        const int off0 = tid * 16,        row0_ = off0 >> 6, colb0 = off0 & 63;
        const int off1 = 4096 + tid * 16, row1_ = off1 >> 6, colb1 = off1 & 63;

        for (int kk = 0; kk < DD / 32; ++kk) {
            const int kbase = kk * 32;
            __builtin_amdgcn_global_load_lds(
                (gvoid_t*)(A + (arow0 + row0_) * DD + kbase + (colb0 >> 1)),
                (lvoid_t*)(ldsA + off0), 16, 0, 0);
            __builtin_amdgcn_global_load_lds(
                (gvoid_t*)(A + (arow0 + row1_) * DD + kbase + (colb1 >> 1)),
                (lvoid_t*)(ldsA + off1), 16, 0, 0);
            __builtin_amdgcn_global_load_lds(
                (gvoid_t*)(Bw + (size_t)(brow0 + row0_) * DD + kbase + (colb0 >> 1)),
                (lvoid_t*)(ldsB + off0), 16, 0, 0);
            __builtin_amdgcn_global_load_lds(
                (gvoid_t*)(Bw + (size_t)(brow0 + row1_) * DD + kbase + (colb1 >> 1)),
                (lvoid_t*)(ldsB + off1), 16, 0, 0);
            __syncthreads();

            const int ml = lane & 15;
            const int kh = (lane >> 4) * 16;
            bf16x8_t av[4], bv[4];
            #pragma unroll
            for (int i = 0; i < 4; ++i) {
                av[i] = *(const bf16x8_t*)(ldsA + (wm * 64 + i * 16 + ml) * 64 + kh);
                bv[i] = *(const bf16x8_t*)(ldsB + (wn * 64 + i * 16 + ml) * 64 + kh);
            }
            #pragma unroll
            for (int i = 0; i < 4; ++i)
                #pragma unroll
                for (int j = 0; j < 4; ++j)
                    acc[i][j] = __builtin_amdgcn_mfma_f32_16x16x32_bf16(av[i], bv[j], acc[i][j], 0, 0, 0);
            __syncthreads();
        }

        const int rq = (lane >> 4) * 4;
        const int cl = lane & 15;
        #pragma unroll
        for (int i = 0; i < 4; ++i) {
            #pragma unroll
            for (int j = 0; j < 4; ++j) {
                const int n = brow0 + wn * 64 + j * 16 + cl;
                const float bb = bias[n];
                #pragma unroll
                for (int q = 0; q < 4; ++q) {
                    const size_t m = arow0 + wm * 64 + i * 16 + rq + q;
                    outr[m * DD + n] = acc[i][j][q] + bb;
                }
            }
        }
        if (gated) {
            __syncthreads();    // drains each wave's C stores (vmcnt 0)
            if (tid == 0)
                __hip_atomic_fetch_add(&cnt[gy], 1, __ATOMIC_RELEASE,
                                       __HIP_MEMORY_SCOPE_AGENT);
        }
        return;
    }

    if (id < ID_GEMM) {
        // ===================== SCAN role (v10 body + gating) =====================
        const int b = id;
        if (tid >= 64) return;
        const int lane = tid;
        const int dof = lane * 4;
        const float alpha = expf(la[0]);
        const float* wbase = outr + b * DD + dof;
        __builtin_amdgcn_s_setprio(1);

        float h[16];
        #pragma unroll
        for (int k = 0; k < 4; ++k) {
            float4 v = *(const float4*)(h0 + b * DD + k * 256 + dof);
            h[k*4+0] = v.x; h[k*4+1] = v.y; h[k*4+2] = v.z; h[k*4+3] = v.w;
        }
        asm volatile("" :: "v"(h[0]), "v"(h[1]), "v"(h[2]), "v"(h[3]),
                           "v"(h[4]), "v"(h[5]), "v"(h[6]), "v"(h[7]),
                           "v"(h[8]), "v"(h[9]), "v"(h[10]), "v"(h[11]),
                           "v"(h[12]), "v"(h[13]), "v"(h[14]), "v"(h[15]));
        __builtin_amdgcn_sched_barrier(0);

        if (gated && lane == 0) {            // rows 0..7 (y=0) must exist
            while (__hip_atomic_load(&cnt[0], __ATOMIC_ACQUIRE,
                                     __HIP_MEMORY_SCOPE_AGENT) < 8)
                __builtin_amdgcn_s_sleep(8);
        }

        // prologue: issue rows 0..7 (32 loads)
        f32x4_t buf[RING][4];
        #pragma unroll
        for (int s = 0; s < RING; ++s) {
            const float* wp = wbase + (size_t)s * BD;
            #pragma unroll
            for (int k = 0; k < 4; ++k)
                asm volatile("global_load_dwordx4 %0, %1, off"
                             : "=v"(buf[s][k]) : "v"(wp + k * 256));
        }

        float r_keep = 0.f;

        for (int tt = 0; tt < TT; tt += 8) {
            // gate this window's refill target rows tt+8..tt+15 (y = tt/8+1)
            if (gated && lane == 0) {
                int y = (tt >> 3) + 1; if (y > 255) y = 255;
                while (__hip_atomic_load(&cnt[y], __ATOMIC_ACQUIRE,
                                         __HIP_MEMORY_SCOPE_AGENT) < 8)
                    __builtin_amdgcn_s_sleep(8);
            }
            #pragma unroll
            for (int g = 0; g < 2; ++g) {
                const int m0 = tt + g * 4;

                asm volatile("s_waitcnt vmcnt(16)" ::: "memory");
                __builtin_amdgcn_sched_barrier(0);

                if ((m0 & 255) == 0) {              // snapshot h_{m0} (chunk head)
                    float* hp = hreg + (size_t)m0 * BD + b * DD;
                    #pragma unroll
                    for (int k = 0; k < 4; ++k) {
                        float4 v; v.x = h[k*4+0]; v.y = h[k*4+1];
                        v.z = h[k*4+2]; v.w = h[k*4+3];
                        *(float4*)(hp + k * 256 + dof) = v;
                    }
                }

                #pragma unroll
                for (int s4 = 0; s4 < 4; ++s4) {
                    const int s = g * 4 + s4;
                    const int m = m0 + s4;
                    float hr[16];
                    float p0 = 0.f, p1 = 0.f, p2 = 0.f, p3 = 0.f;
                    #pragma unroll
                    for (int k = 0; k < 4; ++k) {
                        const f32x4_t w = buf[s][k];
                        hr[k*4+0] = fmaf(alpha, w[0], h[k*4+0]);
                        hr[k*4+1] = fmaf(alpha, w[1], h[k*4+1]);
                        hr[k*4+2] = fmaf(alpha, w[2], h[k*4+2]);
                        hr[k*4+3] = fmaf(alpha, w[3], h[k*4+3]);
                        p0 = fmaf(hr[k*4+0], hr[k*4+0], p0);
                        p1 = fmaf(hr[k*4+1], hr[k*4+1], p1);
                        p2 = fmaf(hr[k*4+2], hr[k*4+2], p2);
                        p3 = fmaf(hr[k*4+3], hr[k*4+3], p3);
                    }
                    const float total = wave_red_sum((p0 + p1) + (p2 + p3));
                    const float rt = __builtin_amdgcn_rsqf(fmaf(total, INVD, EPSV));
                    r_keep = (lane == (m & 63)) ? rt : r_keep;
                    #pragma unroll
                    for (int e = 0; e < 16; ++e) h[e] = rt * hr[e];
                }

                if (g == 1 && (tt & 63) == 56)
                    rtab[(size_t)b * TT + (tt - 56) + lane] = r_keep;

                #pragma unroll
                for (int s4 = 0; s4 < 4; ++s4) {
                    const int s = g * 4 + s4;
                    const float* wp = wbase + (size_t)((m0 + 8 + s4) & (TT - 1)) * BD;
                    #pragma unroll
                    for (int k = 0; k < 4; ++k)
                        asm volatile("global_load_dwordx4 %0, %1, off"
                                     : "=v"(buf[s][k]) : "v"(wp + k * 256));
                }
            }

            if (gated && (tt & 255) == 248 && lane == 0) {
                // chunk (tt+8)/256 fully flushed (rtab) + its head snapshot
                // written earlier; release-publish (waits stores, wb L2).
                __hip_atomic_store(&prog[b], (tt + 8) >> 8, __ATOMIC_RELEASE,
                                   __HIP_MEMORY_SCOPE_AGENT);
            }
        }
        asm volatile("s_waitcnt vmcnt(0)" ::: "memory");
        return;
    }

    // ===================== phase-B role =====================
    {
        const int pid = id - ID_PB;
        const int c = pid >> 6;
        const int col = (pid & 63) * 256 + tid;
        const int b = col >> 10;
        if (gated) {
            if (tid == 0) {
                while (__hip_atomic_load(&prog[b], __ATOMIC_ACQUIRE,
                                         __HIP_MEMORY_SCOPE_AGENT) < c + 1)
                    __builtin_amdgcn_s_sleep(64);
            }
            __syncthreads();
        }
        const float alpha = expf(la[0]);
        const float* rr = rtab + b * TT;
        float h = hreg[(size_t)(c * CH) * BD + col];
        const int t0 = c * CH + 1;
        float w = outr[(size_t)(t0 - 1) * BD + col];
        for (int s = 0; s < CH; ++s) {
            const int t = t0 + s;
            float wnext = 0.f;
            if (s + 1 < CH) wnext = outr[(size_t)t * BD + col];
            const float r = rr[t - 1];
            const float hraw = fmaf(alpha, w, h);
            const float hn = r * hraw;
            const float sg = 1.0f / (1.0f + __expf(-hn));
            outr[(size_t)(t - 1) * BD + col] = hn * hn * sg;
            if ((t & (CH - 1)) != 0 || t == TT)
                hreg[(size_t)t * BD + col] = hn;
            h = hn;
            w = wnext;
        }
    }
}

// ---------------------------------------------------------------------------
extern "C" void kernel_launch(void* const* d_in, const int* in_sizes, int n_in,
                              void* d_out, int out_size, void* d_ws, size_t ws_size,
                              hipStream_t stream) {
    (void)in_sizes; (void)n_in; (void)out_size;
    const float* x    = (const float*)d_in[0];
    const float* h0   = (const float*)d_in[1];
    const float* W    = (const float*)d_in[2];
    const float* bias = (const float*)d_in[3];
    const float* la   = (const float*)d_in[4];

    float* outr = (float*)d_out;                         // [T][B*D] : Wx -> out
    float* hreg = outr + (size_t)TT * BD;                // [T+1][B*D] : h output
    // dead-space layout in hreg (64KB rows):
    //   rows 0..992   : free (scan row-0 + chunk-head snapshots live here)
    //   rows 993..2016: xb  (bf16 x, 64MB)  — clobber-order-safe vs phaseB
    //   rows 2017..2048: wb (bf16 W, 2MB)   — clobbered only by chunk 7 (prog=8)
    unsigned short* xb = (unsigned short*)(hreg + (size_t)993 * BD);
    unsigned short* wb = xb + (size_t)MR * DD;
    float* rtab = (float*)d_ws;                          // [B][T] = 128KB
    int*   cnt  = (int*)d_ws + (size_t)TT * BB;          // 256 ints
    int*   prog = cnt + 256;                             // 16 ints
    const size_t need = (size_t)TT * BB * 4 + (256 + 16) * 4;
    const bool fused = ws_size >= need;

    k_convert<<<2048, 256, 0, stream>>>(x, W, xb, wb);
    if (fused) {
        hipMemsetAsync(cnt, 0, (256 + 16) * sizeof(int), stream);
        k_mega<<<ID_END, 256, 0, stream>>>(xb, wb, bias, outr, h0, la,
                                           hreg, rtab, cnt, prog, 0, 1);
    } else {
        // serial fallback == r10 pipeline, same kernel with gating off
        k_mega<<<2048, 256, 0, stream>>>(xb, wb, bias, outr, h0, la,
                                         hreg, rtab, nullptr, nullptr, ID_GEMM, 0);
        k_mega<<<16, 256, 0, stream>>>(xb, wb, bias, outr, h0, la,
                                       hreg, rtab, nullptr, nullptr, 0, 0);
        k_mega<<<512, 256, 0, stream>>>(xb, wb, bias, outr, h0, la,
                                        hreg, rtab, nullptr, nullptr, ID_PB, 0);
    }
}